// Round 3
// baseline (11554.111 us; speedup 1.0000x reference)
//
#include <hip/hip_runtime.h>

typedef __attribute__((ext_vector_type(8))) short s16x8;
typedef __attribute__((ext_vector_type(4))) float f32x4;

#define B_ 64
#define T_ 512
#define H_ 1024

__device__ __forceinline__ short f2bf(float f) {
  union { float f; unsigned u; } x; x.f = f;
  unsigned r = (x.u + 0x7fffu + ((x.u >> 16) & 1u)) >> 16;  // RNE
  return (short)r;
}
__device__ __forceinline__ float fast_sigmoid(float x) { return 1.f / (1.f + __expf(-x)); }
__device__ __forceinline__ float fast_tanh(float x) {
  float e = __expf(-2.f * fabsf(x));
  float t = (1.f - e) / (1.f + e);
  return copysignf(t, x);
}

// ws layout (rebuilt every call by prep; ws is poisoned 0xAA before each timed call):
//  Wp    [2 layer][128 nb][kh][iter][nf][lane][8]  bf16   32 MB  (block-flat = LDS staging order)
//  bias  [2][4096] fp32 (b_ih+b_hh folded)                32 KB
//  Xp    [T][128 chunk][64 b][8] bf16                     64 MB  (A-chunked layout)
//  hbuf  [2 layer][2 parity][128 chunk][64 b][8] bf16    512 KB
//  flags [2 layer][128 nb] ints spread by 16 ints         16 KB
__global__ void prep_kernel(const float* __restrict__ input_, const float* __restrict__ hx,
                            const float* __restrict__ cx, const float* __restrict__ W_ih,
                            const float* __restrict__ W_hh, const float* __restrict__ b_ih,
                            const float* __restrict__ b_hh,
                            short* __restrict__ Wp, float* __restrict__ bias,
                            short* __restrict__ Xp, short* __restrict__ hbuf,
                            int* __restrict__ flags)
{
  for (long idx = (long)blockIdx.x * blockDim.x + threadIdx.x; idx < 33554432L;
       idx += (long)gridDim.x * blockDim.x) {
    {
      // Xp[((t*128 + c)*64 + b)*8 + e] = x[b][t][c*8+e]
      int e = idx & 7;
      int b = (idx >> 3) & 63;
      long tc = idx >> 9;
      int c = (int)(tc & 127);
      int t = (int)(tc >> 7);
      Xp[idx] = f2bf(input_[((long)b * T_ + t) * H_ + c * 8 + e]);
    }
    if (idx < 16777216L) {
      int blockf = (int)(idx >> 16);        // layer*128 + nb
      int layer = blockf >> 7, nb = blockf & 127;
      int r = (int)(idx & 65535);
      int e = r & 7;
      int lane = (r >> 3) & 63;
      int nf = (r >> 9) & 1;
      int it = (r >> 10) & 31;
      int kh = (r >> 15) & 1;
      int lo = lane & 15, quad = lane >> 4;
      int ntile = nf * 16 + lo;             // 0..31
      int g = ntile >> 3, col = ntile & 7;
      int j = g * 1024 + nb * 8 + col;      // gate row
      int k = kh * 1024 + it * 32 + quad * 8 + e;
      float v = (k < H_) ? W_ih[((long)(layer << 12) + j) * H_ + k]
                         : W_hh[((long)(layer << 12) + j) * H_ + (k - H_)];
      Wp[idx] = f2bf(v);
    }
    if (idx < 8192) bias[idx] = b_ih[idx] + b_hh[idx];
    if (idx < 65536) {
      // h init into parity-1 buffers (read at t=0 via (t+1)&1 == 1)
      int b = (int)(idx >> 10), n = (int)(idx & 1023);
      int pi = (n >> 3) * 512 + b * 8 + (n & 7);
      hbuf[(0 * 2 + 1) * 65536 + pi] = f2bf(hx[(b * 2 + 0) * H_ + n]);
      hbuf[(1 * 2 + 1) * 65536 + pi] = f2bf(hx[(b * 2 + 1) * H_ + n]);
    }
    if (idx < 4096) flags[idx] = 0;
  }
}

// Persistent kernel: grid 256 (1 block/CU), block 256 = 4 waves.
// block: layer = blk&1, nb = blk>>1 (0..127): owns gate rows {g*1024+nb*8+col}, all 64 b.
// wave = (mh = wave&1 -> batches mh*32..+32, kh = wave>>1 -> K half).
__global__ __launch_bounds__(256, 1)
void lstm_persist(const short* __restrict__ Wp, const float* __restrict__ bias,
                  const short* __restrict__ Xp, short* __restrict__ hbuf,
                  int* __restrict__ flags, const float* __restrict__ cx,
                  float* __restrict__ out)
{
  __shared__ short wl[65536];       // 128 KB weight slice
  __shared__ float red[2560];       // [2 mh][64 lane][20] cross-kh partials

  const int layer = blockIdx.x & 1;
  const int nb = blockIdx.x >> 1;
  const int tid = threadIdx.x;
  const int wave = tid >> 6;
  const int lane = tid & 63;
  const int quad = lane >> 4;
  const int lo = lane & 15;
  const int mh = wave & 1;
  const int kh = wave >> 1;

  // ---- stage weights to LDS (one time) ----
  {
    const s16x8* wsrc = (const s16x8*)(Wp + ((size_t)(layer * 128 + nb) << 16));
    s16x8* wd = (s16x8*)wl;
    for (int i = tid; i < 8192; i += 256) wd[i] = wsrc[i];
  }

  // ---- per-lane constants ----
  const int col = lo & 7;
  const int jb = nb * 8 + col;
  const float bi = bias[layer * 4096 + jb];
  const float bf_ = bias[layer * 4096 + 1024 + jb];
  const float bg = bias[layer * 4096 + 2048 + jb];
  const float bo = bias[layer * 4096 + 3072 + jb];

  float creg[2][4];
#pragma unroll
  for (int mt = 0; mt < 2; ++mt)
#pragma unroll
    for (int r = 0; r < 4; ++r) {
      int b = mh * 32 + mt * 16 + quad * 4 + r;
      creg[mt][r] = cx[((long)b * 2 + layer) * H_ + jb];
    }

  int* myslot = flags + (layer * 128 + nb) * 16;
  const int* f0a = flags + (0 * 128 + lane) * 16;
  const int* f0b = flags + (0 * 128 + 64 + lane) * 16;
  const int* f1a = flags + (1 * 128 + lane) * 16 + 0;  // layer1 slots
  const int* f1b = flags + (1 * 128 + 64 + lane) * 16;

  __syncthreads();   // weights staged

  for (int t = 0; t < T_; ++t) {
    // ---- wait phase (wave 0 polls, everyone holds at barrier) ----
    if (wave == 0) {
      const int T0 = (layer == 0) ? t : t + 1;       // min over layer-0 slots
      const int T1 = (layer == 0) ? t - 1 : t;       // min over layer-1 slots
      while (true) {
        int a = __hip_atomic_load(f0a, __ATOMIC_RELAXED, __HIP_MEMORY_SCOPE_AGENT);
        int b = __hip_atomic_load(f0b, __ATOMIC_RELAXED, __HIP_MEMORY_SCOPE_AGENT);
        int c = __hip_atomic_load(f1a, __ATOMIC_RELAXED, __HIP_MEMORY_SCOPE_AGENT);
        int d = __hip_atomic_load(f1b, __ATOMIC_RELAXED, __HIP_MEMORY_SCOPE_AGENT);
        if (__all(a >= T0 && b >= T0 && c >= T1 && d >= T1)) break;
        __builtin_amdgcn_s_sleep(8);
      }
      __threadfence();   // acquire: invalidate stale L1/L2 before reading h
    }
    __syncthreads();   // (a)

    // ---- A source for this wave ----
    const short* Asrc;
    if (layer == 0)
      Asrc = (kh == 0) ? (Xp + (size_t)t * 65536)
                       : (hbuf + (size_t)(0 * 2 + ((t + 1) & 1)) * 65536);
    else
      Asrc = (kh == 0) ? (hbuf + (size_t)(0 * 2 + (t & 1)) * 65536)
                       : (hbuf + (size_t)(1 * 2 + ((t + 1) & 1)) * 65536);
    const short* pAq = Asrc + mh * 256 + lo * 8 + quad * 512;

    f32x4 acc00 = {0.f, 0.f, 0.f, 0.f}, acc01 = {0.f, 0.f, 0.f, 0.f};
    f32x4 acc10 = {0.f, 0.f, 0.f, 0.f}, acc11 = {0.f, 0.f, 0.f, 0.f};

    const short* wbase = wl + (size_t)kh * 32768 + lane * 8;
#pragma unroll 4
    for (int it = 0; it < 32; ++it) {
      const s16x8 A0 = *(const s16x8*)(pAq + it * 2048);
      const s16x8 A1 = *(const s16x8*)(pAq + it * 2048 + 128);
      const s16x8 B0 = *(const s16x8*)(wbase + it * 1024);
      const s16x8 B1 = *(const s16x8*)(wbase + it * 1024 + 512);
      acc00 = __builtin_amdgcn_mfma_f32_16x16x32_bf16(A0, B0, acc00, 0, 0, 0);
      acc01 = __builtin_amdgcn_mfma_f32_16x16x32_bf16(A0, B1, acc01, 0, 0, 0);
      acc10 = __builtin_amdgcn_mfma_f32_16x16x32_bf16(A1, B0, acc10, 0, 0, 0);
      acc11 = __builtin_amdgcn_mfma_f32_16x16x32_bf16(A1, B1, acc11, 0, 0, 0);
    }

    // ---- cross-kh reduction ----
    if (kh == 1) {
      float* rp = red + (mh * 64 + lane) * 20;
      *(f32x4*)(rp + 0) = acc00;
      *(f32x4*)(rp + 4) = acc01;
      *(f32x4*)(rp + 8) = acc10;
      *(f32x4*)(rp + 12) = acc11;
    }
    __syncthreads();   // (b)

    if (kh == 0) {
      const float* rp = red + (mh * 64 + lane) * 20;
      acc00 += *(const f32x4*)(rp + 0);
      acc01 += *(const f32x4*)(rp + 4);
      acc10 += *(const f32x4*)(rp + 8);
      acc11 += *(const f32x4*)(rp + 12);

      short* hdst = hbuf + (size_t)(layer * 2 + (t & 1)) * 65536 + nb * 512;
#pragma unroll
      for (int mt = 0; mt < 2; ++mt) {
        f32x4 g0 = mt == 0 ? acc00 : acc10;   // nf=0: i (lo<8) / f (lo>=8)
        f32x4 g1 = mt == 0 ? acc01 : acc11;   // nf=1: g (lo<8) / o (lo>=8)
#pragma unroll
        for (int r = 0; r < 4; ++r) {
          float x0 = g0[r], x1 = g1[r];
          float y0 = __shfl_xor(x0, 8);
          float y1 = __shfl_xor(x1, 8);
          bool hi = (lo >= 8);
          float ig = (hi ? y0 : x0) + bi;
          float fg = (hi ? x0 : y0) + bf_;
          float gg = (hi ? y1 : x1) + bg;
          float og = (hi ? x1 : y1) + bo;
          float cp = creg[mt][r];
          float si = fast_sigmoid(ig), sf = fast_sigmoid(fg), so = fast_sigmoid(og);
          float cn = sf * cp + si * fast_tanh(gg);
          float hn = so * fast_tanh(cn);
          creg[mt][r] = cn;
          if (lo < 8) {
            int b = mh * 32 + mt * 16 + quad * 4 + r;
            hdst[b * 8 + lo] = f2bf(hn);
            if (layer) {
              out[((size_t)b * T_ + t) * H_ + nb * 8 + lo] = hn;
              if (t == T_ - 1) {
                out[33554432L + (long)b * H_ + nb * 8 + lo] = hn;
                out[33554432L + 65536 + (long)b * H_ + nb * 8 + lo] = cn;
              }
            }
          }
        }
      }
    }
    __syncthreads();   // (c): all h-stores issued+complete (vmcnt drained per-thread)

    if (tid == 0) {
      __threadfence();  // release: write back L2 so other XCDs see h[t]
      __hip_atomic_store(myslot, t + 1, __ATOMIC_RELAXED, __HIP_MEMORY_SCOPE_AGENT);
    }
  }
}

extern "C" void kernel_launch(void* const* d_in, const int* in_sizes, int n_in,
                              void* d_out, int out_size, void* d_ws, size_t ws_size,
                              hipStream_t stream)
{
  const float* input_ = (const float*)d_in[0];
  const float* hx   = (const float*)d_in[1];
  const float* cx   = (const float*)d_in[2];
  const float* W_ih = (const float*)d_in[3];
  const float* W_hh = (const float*)d_in[4];
  const float* b_ih = (const float*)d_in[5];
  const float* b_hh = (const float*)d_in[6];
  float* out = (float*)d_out;

  char* w = (char*)d_ws;
  size_t off = 0;
  short* Wp   = (short*)(w + off); off += 33554432;   // 32 MB
  float* bias = (float*)(w + off); off += 32768;
  short* Xp   = (short*)(w + off); off += 67108864;   // 64 MB
  short* hbuf = (short*)(w + off); off += 524288;     // 2 layer x 2 parity x 128 KB
  int*   flags = (int*)(w + off);  off += 16384;

  hipLaunchKernelGGL(prep_kernel, dim3(4096), dim3(256), 0, stream,
                     input_, hx, cx, W_ih, W_hh, b_ih, b_hh,
                     Wp, bias, Xp, hbuf, flags);

  hipLaunchKernelGGL(lstm_persist, dim3(256), dim3(256), 0, stream,
                     Wp, bias, Xp, hbuf, flags, cx, out);
}